// Round 5
// baseline (213.192 us; speedup 1.0000x reference)
//
#include <hip/hip_runtime.h>
#include <math.h>

// Problem constants (fixed by reference)
#define B_ 8
#define N_ 384
#define D_ 256
#define H_ 1024

typedef __bf16 bh;
typedef __bf16 bf16x8 __attribute__((ext_vector_type(8)));
typedef float  f32x4  __attribute__((ext_vector_type(4)));
typedef _Float16 h2 __attribute__((ext_vector_type(2)));

#define LDB 72    // LDS row stride (bf16) for 64-wide K tiles: 144 B rows, <=2-way banks

#if __has_builtin(__builtin_amdgcn_fdot2)
#define FDOT2(a,b,c) __builtin_amdgcn_fdot2((a),(b),(c),false)
#else
#define FDOT2(a,b,c) ((c) + (float)(a).x*(float)(b).x + (float)(a).y*(float)(b).y)
#endif

__device__ inline h2 habs2(h2 x) {
    unsigned u = __builtin_bit_cast(unsigned, x) & 0x7fff7fffu;
    return __builtin_bit_cast(h2, u);
}

// split fp32 -> hi + lo bf16 (3xbf16 trick: a*b ~= ah*bh + ah*bl + al*bh, rel err ~2^-16)
__device__ inline void split2(float v, bh& h, bh& l) {
    h = (bh)v;
    l = (bh)(v - (float)h);
}

__device__ inline void split8(const float* f, bf16x8& h8, bf16x8& l8) {
    #pragma unroll
    for (int i = 0; i < 8; i++) { bh h, l; split2(f[i], h, l); h8[i] = h; l8[i] = l; }
}

// box_num is logically int64; harness may hand int32. box_num >= 1 always, so
// int64-LE layout has all odd words zero -> runtime-detectable.
__device__ inline int load_boxnum(const int* __restrict__ p, int b) {
    bool is64 = ((p[1] | p[3] | p[5] | p[7]) == 0);
    return is64 ? p[2 * b] : p[b];
}

// ---------------- GEMM1: c1 = relu(x @ fc1_w^T + fc1_b), 64x64 tiles, inline fp32->hi/lo split ----------------
// grid (16,48) = 768 blocks = 3/CU balanced.
__global__ __launch_bounds__(256) void gemm1_kernel(
        const float* __restrict__ A,     // (rows,256) fp32 x
        const float* __restrict__ W,     // (1024,256) fp32 fc1_w
        const float* __restrict__ bias,
        bh* __restrict__ Ch, bh* __restrict__ Cl)   // (rows,1024) hi/lo
{
    __shared__ __align__(16) bh AhS[64 * LDB], AlS[64 * LDB], WhS[64 * LDB], WlS[64 * LDB];  // 36.9 KB
    const int tid = threadIdx.x;
    const int m0 = blockIdx.y * 64, n0 = blockIdx.x * 64;
    const int r = tid >> 2, kq = (tid & 3) * 16;   // staging: 4 threads/row x 16 elems
    const int lane = tid & 63, wv_ = tid >> 6;
    const int wm = (wv_ & 1) * 32, wn = (wv_ >> 1) * 32;
    const int l15 = lane & 15, q = lane >> 4;

    f32x4 acc[2][2] = {};
    for (int k0 = 0; k0 < D_; k0 += 64) {
        const float* ap = A + (size_t)(m0 + r) * D_ + k0 + kq;
        const float* wp = W + (size_t)(n0 + r) * D_ + k0 + kq;
        float af[16], wf[16];
        #pragma unroll
        for (int u = 0; u < 4; u++) {
            *(float4*)&af[4 * u] = *(const float4*)(ap + 4 * u);
            *(float4*)&wf[4 * u] = *(const float4*)(wp + 4 * u);
        }
        bf16x8 ah0, ah1, al0, al1, wh0, wh1, wl0, wl1;
        split8(af,     ah0, al0); split8(af + 8, ah1, al1);
        split8(wf,     wh0, wl0); split8(wf + 8, wh1, wl1);
        __syncthreads();
        *(bf16x8*)&AhS[r * LDB + kq]     = ah0;  *(bf16x8*)&AhS[r * LDB + kq + 8] = ah1;
        *(bf16x8*)&AlS[r * LDB + kq]     = al0;  *(bf16x8*)&AlS[r * LDB + kq + 8] = al1;
        *(bf16x8*)&WhS[r * LDB + kq]     = wh0;  *(bf16x8*)&WhS[r * LDB + kq + 8] = wh1;
        *(bf16x8*)&WlS[r * LDB + kq]     = wl0;  *(bf16x8*)&WlS[r * LDB + kq + 8] = wl1;
        __syncthreads();
        #pragma unroll
        for (int ks = 0; ks < 2; ks++) {
            const int kb = ks * 32 + q * 8;
            bf16x8 fah[2], fal[2], fwh[2], fwl[2];
            #pragma unroll
            for (int mi = 0; mi < 2; mi++) {
                int row = wm + mi * 16 + l15;
                fah[mi] = *(const bf16x8*)&AhS[row * LDB + kb];
                fal[mi] = *(const bf16x8*)&AlS[row * LDB + kb];
            }
            #pragma unroll
            for (int ni = 0; ni < 2; ni++) {
                int row = wn + ni * 16 + l15;
                fwh[ni] = *(const bf16x8*)&WhS[row * LDB + kb];
                fwl[ni] = *(const bf16x8*)&WlS[row * LDB + kb];
            }
            #pragma unroll
            for (int mi = 0; mi < 2; mi++)
                #pragma unroll
                for (int ni = 0; ni < 2; ni++) {
                    acc[mi][ni] = __builtin_amdgcn_mfma_f32_16x16x32_bf16(fah[mi], fwh[ni], acc[mi][ni], 0, 0, 0);
                    acc[mi][ni] = __builtin_amdgcn_mfma_f32_16x16x32_bf16(fah[mi], fwl[ni], acc[mi][ni], 0, 0, 0);
                    acc[mi][ni] = __builtin_amdgcn_mfma_f32_16x16x32_bf16(fal[mi], fwh[ni], acc[mi][ni], 0, 0, 0);
                }
        }
    }
    #pragma unroll
    for (int ni = 0; ni < 2; ni++) {
        int col = n0 + wn + ni * 16 + l15;
        float bb = bias[col];
        #pragma unroll
        for (int mi = 0; mi < 2; mi++)
            #pragma unroll
            for (int reg = 0; reg < 4; reg++) {
                int row = m0 + wm + mi * 16 + q * 4 + reg;
                float v = fmaxf(acc[mi][ni][reg] + bb, 0.f);
                bh h, l; split2(v, h, l);
                size_t off = (size_t)row * H_ + col;
                Ch[off] = h; Cl[off] = l;
            }
    }
}

// ---------------- GEMM2: xhat = c1 @ fc2_w^T + fc2_b; 96x32 tiles; grid 8x32 = 256 blocks = 1/CU ----------------
// 384 threads = 6 waves, each wave 16 rows x 32 cols. Also zeroes the dist stripe counters.
__global__ __launch_bounds__(384) void gemm2_kernel(
        const bh* __restrict__ Ah_, const bh* __restrict__ Al_,  // (rows,1024) c1 hi/lo
        const float* __restrict__ W,     // (256,1024) fp32 fc2_w, split inline
        const float* __restrict__ bias,
        float* __restrict__ C, _Float16* __restrict__ C16,       // (rows,256)
        int* __restrict__ cnt)                                   // 48 stripe counters (zeroed here)
{
    if (blockIdx.x == 0 && blockIdx.y == 0 && threadIdx.x < 48) cnt[threadIdx.x] = 0;
    __shared__ __align__(16) bh AhS[96 * LDB], AlS[96 * LDB], WhS[32 * LDB], WlS[32 * LDB];  // 36.9 KB
    const int tid = threadIdx.x;
    const int m0 = blockIdx.y * 96, n0 = blockIdx.x * 32;
    const int lane = tid & 63, wv_ = tid >> 6;     // 0..5
    const int wm = wv_ * 16;
    const int l15 = lane & 15, q = lane >> 4;
    const int r = tid >> 2, kq = (tid & 3) * 16;   // A staging: 96 rows x 4 thr x 16 elems
    const int rw = (tid & 255) >> 3, kw = (tid & 7) * 8;  // W staging (tid<256): 32 rows x 8 thr x 8 floats

    f32x4 acc[2] = {};
    for (int k0 = 0; k0 < H_; k0 += 64) {
        const bh* pah = Ah_ + (size_t)(m0 + r) * H_ + k0 + kq;
        const bh* pal = Al_ + (size_t)(m0 + r) * H_ + k0 + kq;
        bf16x8 a0 = *(const bf16x8*)pah, a1 = *(const bf16x8*)(pah + 8);
        bf16x8 l0 = *(const bf16x8*)pal, l1 = *(const bf16x8*)(pal + 8);
        bf16x8 wh8, wl8;
        if (tid < 256) {
            const float* wp = W + (size_t)(n0 + rw) * H_ + k0 + kw;
            float wf[8];
            *(float4*)&wf[0] = *(const float4*)wp;
            *(float4*)&wf[4] = *(const float4*)(wp + 4);
            split8(wf, wh8, wl8);
        }
        __syncthreads();
        *(bf16x8*)&AhS[r * LDB + kq] = a0;  *(bf16x8*)&AhS[r * LDB + kq + 8] = a1;
        *(bf16x8*)&AlS[r * LDB + kq] = l0;  *(bf16x8*)&AlS[r * LDB + kq + 8] = l1;
        if (tid < 256) {
            *(bf16x8*)&WhS[rw * LDB + kw] = wh8;
            *(bf16x8*)&WlS[rw * LDB + kw] = wl8;
        }
        __syncthreads();
        #pragma unroll
        for (int ks = 0; ks < 2; ks++) {
            const int kb = ks * 32 + q * 8;
            bf16x8 fah = *(const bf16x8*)&AhS[(wm + l15) * LDB + kb];
            bf16x8 fal = *(const bf16x8*)&AlS[(wm + l15) * LDB + kb];
            #pragma unroll
            for (int ni = 0; ni < 2; ni++) {
                int row = ni * 16 + l15;
                bf16x8 fwh = *(const bf16x8*)&WhS[row * LDB + kb];
                bf16x8 fwl = *(const bf16x8*)&WlS[row * LDB + kb];
                acc[ni] = __builtin_amdgcn_mfma_f32_16x16x32_bf16(fah, fwh, acc[ni], 0, 0, 0);
                acc[ni] = __builtin_amdgcn_mfma_f32_16x16x32_bf16(fah, fwl, acc[ni], 0, 0, 0);
                acc[ni] = __builtin_amdgcn_mfma_f32_16x16x32_bf16(fal, fwh, acc[ni], 0, 0, 0);
            }
        }
    }
    #pragma unroll
    for (int ni = 0; ni < 2; ni++) {
        int col = n0 + ni * 16 + l15;
        float bb = bias[col];
        #pragma unroll
        for (int reg = 0; reg < 4; reg++) {
            int row = m0 + wm + q * 4 + reg;
            float v = acc[ni][reg] + bb;
            C[(size_t)row * D_ + col] = v;
            C16[(size_t)row * D_ + col] = (_Float16)v;
        }
    }
}

// ---------------- dist + fused last-finisher softmax ----------------
// Upper-triangle 64x64 tiles (21/batch, 168 blocks), mirror-written.
// Each row-stripe (64 rows) is touched by exactly 6 blocks (5 off-diag + 1 diag).
// After tile writes: __threadfence -> atomicAdd per touched stripe; the block that
// brings a stripe to 6 runs the softmax for those 64 rows (dispatch-order independent,
// no spinning -> no deadlock; device-scope atomics + fences per G16).
#define DLX 132   // row-slot stride (128 rows + 4 pad); 528 B per k2 -> 16B-aligned, reads <=2-way banks
__global__ __launch_bounds__(512) void dist_kernel(const _Float16* __restrict__ xh16,
                                                   const float* __restrict__ w,
                                                   const int* __restrict__ box_num,
                                                   const float* __restrict__ adj,
                                                   float* __restrict__ dist,
                                                   int* __restrict__ cnt) {
    __shared__ __align__(16) unsigned X[128 * DLX];   // [k2][row: 0-63 = i-block, 64-127 = j-block]
    __shared__ unsigned WkS[128];
    __shared__ int finS[2];
    const int bidx = blockIdx.x;
    const int b = bidx / 21;
    int p = bidx % 21;
    int ti = 0;
    while (p >= 6 - ti) { p -= 6 - ti; ti++; }
    const int tj = ti + p;
    const int i0 = ti * 64, j0 = tj * 64;
    const int tid = threadIdx.x;
    const int lane = tid & 63;

    // sum(learn_w) per wave
    float sumw = w[lane] + w[lane + 64] + w[lane + 128] + w[lane + 192];
    #pragma unroll
    for (int off = 32; off > 0; off >>= 1) sumw += __shfl_xor(sumw, off);

    // w pairs as fp16x2 in LDS
    if (tid < 128) {
        float2 wp = *(const float2*)&w[2 * tid];
        h2 wv = {(_Float16)wp.x, (_Float16)wp.y};
        WkS[tid] = __builtin_bit_cast(unsigned, wv);
    }

    // stage 128 rows x 256 dims fp16 (64 KB) transposed to k2-major
    const int sr = tid >> 2, koff = (tid & 3) * 64;
    const int grow = (sr < 64) ? (i0 + sr) : (j0 + sr - 64);
    const _Float16* src = xh16 + ((size_t)b * N_ + grow) * D_ + koff;
    #pragma unroll
    for (int ld = 0; ld < 8; ld++) {
        uint4 v = *(const uint4*)(src + ld * 8);
        int k2 = (koff >> 1) + ld * 4;
        X[(k2 + 0) * DLX + sr] = v.x;
        X[(k2 + 1) * DLX + sr] = v.y;
        X[(k2 + 2) * DLX + sr] = v.z;
        X[(k2 + 3) * DLX + sr] = v.w;
    }
    __syncthreads();

    const int tx = tid & 31, ty = tid >> 5;   // 16x32 thread grid, 4x2 micro
    float acc[4][2] = {};
    #pragma unroll 4
    for (int k2 = 0; k2 < 128; k2++) {
        uint4 av = *(const uint4*)&X[k2 * DLX + ty * 4];        // 4 i-rows (broadcast x32)
        uint2 bv = *(const uint2*)&X[k2 * DLX + 64 + tx * 2];   // 2 j-rows (2-way banks)
        h2 wv = __builtin_bit_cast(h2, WkS[k2]);
        h2 ai[4] = {__builtin_bit_cast(h2, av.x), __builtin_bit_cast(h2, av.y),
                    __builtin_bit_cast(h2, av.z), __builtin_bit_cast(h2, av.w)};
        h2 bj[2] = {__builtin_bit_cast(h2, bv.x), __builtin_bit_cast(h2, bv.y)};
        #pragma unroll
        for (int ii = 0; ii < 4; ii++)
            #pragma unroll
            for (int jj = 0; jj < 2; jj++) {
                h2 d = habs2(ai[ii] - bj[jj]);
                acc[ii][jj] = FDOT2(d, wv, acc[ii][jj]);
            }
    }

    const int bn = load_boxnum(box_num, b);
    float m[4][2];
    #pragma unroll
    for (int ii = 0; ii < 4; ii++) {
        int i = i0 + ty * 4 + ii;
        bool vi = i < bn;
        #pragma unroll
        for (int jj = 0; jj < 2; jj++) {
            int j = j0 + tx * 2 + jj;
            float v = acc[ii][jj];
            if (!(vi && (j < bn))) v -= sumw;
            m[ii][jj] = v > 0.f ? v : 0.01f * v;
        }
    }
    float* base = dist + (size_t)b * N_ * N_;
    // primary tile: rows i, cols j (coalesced float2)
    #pragma unroll
    for (int ii = 0; ii < 4; ii++) {
        int i = i0 + ty * 4 + ii;
        float2 o = {m[ii][0], m[ii][1]};
        *(float2*)&base[(size_t)i * N_ + j0 + tx * 2] = o;
    }
    // mirror tile: rows j, cols i (diagonal tiles double-write identical bits - benign)
    #pragma unroll
    for (int jj = 0; jj < 2; jj++) {
        int j = j0 + tx * 2 + jj;
        float4 o = {m[0][jj], m[1][jj], m[2][jj], m[3][jj]};
        *(float4*)&base[(size_t)j * N_ + i0 + ty * 4] = o;
    }

    // ---- last-finisher softmax ----
    __threadfence();          // release: make this block's tile stores device-visible
    __syncthreads();          // all threads' stores + fences complete before the atomics
    if (tid == 0) {
        int f0 = -1, f1 = -1;
        if (atomicAdd(&cnt[b * 6 + ti], 1) == 5) f0 = ti;
        if (ti != tj) {
            if (atomicAdd(&cnt[b * 6 + tj], 1) == 5) f1 = tj;
        }
        finS[0] = f0; finS[1] = f1;
    }
    __syncthreads();
    #pragma unroll
    for (int fi = 0; fi < 2; fi++) {
        const int s = finS[fi];
        if (s < 0) continue;
        __threadfence();      // acquire: see the other 5 blocks' stripe writes
        const int wv8 = tid >> 6, t = tid & 63;   // 8 waves x 8 rows = 64 rows
        for (int rr = 0; rr < 8; rr++) {
            const int row = b * N_ + s * 64 + wv8 * 8 + rr;
            float* prow = dist + (size_t)row * N_;
            const float* arow = adj + (size_t)row * N_;
            float v[6];
            float mx = -1e30f;
            #pragma unroll
            for (int qq = 0; qq < 6; qq++) { v[qq] = prow[t + qq * 64]; mx = fmaxf(mx, v[qq]); }
            #pragma unroll
            for (int off = 32; off > 0; off >>= 1) mx = fmaxf(mx, __shfl_xor(mx, off));
            float e[6];
            float sum = 0.f;
            #pragma unroll
            for (int qq = 0; qq < 6; qq++) { e[qq] = arow[t + qq * 64] * expf(v[qq] - mx); sum += e[qq]; }
            #pragma unroll
            for (int off = 32; off > 0; off >>= 1) sum += __shfl_xor(sum, off);
            float inv = 1.0f / sum;
            #pragma unroll
            for (int qq = 0; qq < 6; qq++) prow[t + qq * 64] = e[qq] * inv + 1e-10f;
        }
    }
}

extern "C" void kernel_launch(void* const* d_in, const int* in_sizes, int n_in,
                              void* d_out, int out_size, void* d_ws, size_t ws_size,
                              hipStream_t stream) {
    const float* x       = (const float*)d_in[0];
    const float* adj     = (const float*)d_in[1];
    const int*   box_num = (const int*)d_in[2];
    const float* fc1_w   = (const float*)d_in[3];
    const float* fc1_b   = (const float*)d_in[4];
    const float* fc2_w   = (const float*)d_in[5];
    const float* fc2_b   = (const float*)d_in[6];
    const float* learn_w = (const float*)d_in[7];

    float* soft_adj = (float*)d_out;
    float* xhat     = (float*)d_out + (size_t)B_ * N_ * N_;

    const int BN = B_ * N_;  // 3072

    // ws layout: [x16 fp16 (1.5 MB)] [cnt 48 ints (pad 256 B)] [chunk: c1h|c1l (bf16)]
    _Float16* xh16 = (_Float16*)d_ws;
    int* cnt = (int*)((char*)d_ws + (size_t)BN * D_ * 2);
    bh* cbase = (bh*)((char*)cnt + 256);
    const size_t fixed_bytes = (size_t)BN * D_ * 2 + 256;
    const size_t per_row = (size_t)H_ * 2 * 2;   // c1 hi+lo bytes per row = 4096

    long long avail = (long long)ws_size - (long long)fixed_bytes;
    long long mr = (avail > 0) ? (avail / (long long)per_row) : 0;
    if (mr > BN) mr = BN;
    mr -= mr % 192;          // chunk granularity: lcm(gemm1 64-row, gemm2 96-row)
    if (mr < 192) mr = 192;  // ws is 256 MiB in this harness; single-chunk path in practice
    const int max_rows = (int)mr;

    for (int m0 = 0; m0 < BN; m0 += max_rows) {
        int rows = BN - m0; if (rows > max_rows) rows = max_rows;
        bh* c1h = cbase;
        bh* c1l = c1h + (size_t)max_rows * H_;

        dim3 g1(H_ / 64, rows / 64);
        gemm1_kernel<<<g1, 256, 0, stream>>>(x + (size_t)m0 * D_, fc1_w, fc1_b, c1h, c1l);
        dim3 g2(D_ / 32, rows / 96);
        gemm2_kernel<<<g2, 384, 0, stream>>>(c1h, c1l, fc2_w, fc2_b,
                                             xhat + (size_t)m0 * D_, xh16 + (size_t)m0 * D_, cnt);
    }

    dist_kernel<<<B_ * 21, 512, 0, stream>>>(xh16, learn_w, box_num, adj, soft_adj, cnt);
}

// Round 6
// 125.746 us; speedup vs baseline: 1.6954x; 1.6954x over previous
//
#include <hip/hip_runtime.h>
#include <math.h>

// Problem constants (fixed by reference)
#define B_ 8
#define N_ 384
#define D_ 256
#define H_ 1024

typedef __bf16 bh;
typedef __bf16 bf16x8 __attribute__((ext_vector_type(8)));
typedef float  f32x4  __attribute__((ext_vector_type(4)));
typedef _Float16 h2 __attribute__((ext_vector_type(2)));

#define LDB 72    // LDS row stride (bf16) for 64-wide K tiles: 144 B rows, <=2-way banks

#if __has_builtin(__builtin_amdgcn_fdot2)
#define FDOT2(a,b,c) __builtin_amdgcn_fdot2((a),(b),(c),false)
#else
#define FDOT2(a,b,c) ((c) + (float)(a).x*(float)(b).x + (float)(a).y*(float)(b).y)
#endif

__device__ inline h2 habs2(h2 x) {
    unsigned u = __builtin_bit_cast(unsigned, x) & 0x7fff7fffu;
    return __builtin_bit_cast(h2, u);
}

// split fp32 -> hi + lo bf16 (3xbf16 trick: a*b ~= ah*bh + ah*bl + al*bh, rel err ~2^-16)
__device__ inline void split2(float v, bh& h, bh& l) {
    h = (bh)v;
    l = (bh)(v - (float)h);
}

__device__ inline void split8(const float* f, bf16x8& h8, bf16x8& l8) {
    #pragma unroll
    for (int i = 0; i < 8; i++) { bh h, l; split2(f[i], h, l); h8[i] = h; l8[i] = l; }
}

// box_num is logically int64; harness may hand int32. box_num >= 1 always, so
// int64-LE layout has all odd words zero -> runtime-detectable.
__device__ inline int load_boxnum(const int* __restrict__ p, int b) {
    bool is64 = ((p[1] | p[3] | p[5] | p[7]) == 0);
    return is64 ? p[2 * b] : p[b];
}

// ---------------- GEMM1: c1 = relu(x @ fc1_w^T + fc1_b), 64x64 tiles, inline fp32->hi/lo split ----------------
// grid (16,48) = 768 blocks = 3/CU balanced.
__global__ __launch_bounds__(256) void gemm1_kernel(
        const float* __restrict__ A,     // (rows,256) fp32 x
        const float* __restrict__ W,     // (1024,256) fp32 fc1_w
        const float* __restrict__ bias,
        bh* __restrict__ Ch, bh* __restrict__ Cl)   // (rows,1024) hi/lo
{
    __shared__ __align__(16) bh AhS[64 * LDB], AlS[64 * LDB], WhS[64 * LDB], WlS[64 * LDB];  // 36.9 KB
    const int tid = threadIdx.x;
    const int m0 = blockIdx.y * 64, n0 = blockIdx.x * 64;
    const int r = tid >> 2, kq = (tid & 3) * 16;   // staging: 4 threads/row x 16 elems
    const int lane = tid & 63, wv_ = tid >> 6;
    const int wm = (wv_ & 1) * 32, wn = (wv_ >> 1) * 32;
    const int l15 = lane & 15, q = lane >> 4;

    f32x4 acc[2][2] = {};
    for (int k0 = 0; k0 < D_; k0 += 64) {
        const float* ap = A + (size_t)(m0 + r) * D_ + k0 + kq;
        const float* wp = W + (size_t)(n0 + r) * D_ + k0 + kq;
        float af[16], wf[16];
        #pragma unroll
        for (int u = 0; u < 4; u++) {
            *(float4*)&af[4 * u] = *(const float4*)(ap + 4 * u);
            *(float4*)&wf[4 * u] = *(const float4*)(wp + 4 * u);
        }
        bf16x8 ah0, ah1, al0, al1, wh0, wh1, wl0, wl1;
        split8(af,     ah0, al0); split8(af + 8, ah1, al1);
        split8(wf,     wh0, wl0); split8(wf + 8, wh1, wl1);
        __syncthreads();
        *(bf16x8*)&AhS[r * LDB + kq]     = ah0;  *(bf16x8*)&AhS[r * LDB + kq + 8] = ah1;
        *(bf16x8*)&AlS[r * LDB + kq]     = al0;  *(bf16x8*)&AlS[r * LDB + kq + 8] = al1;
        *(bf16x8*)&WhS[r * LDB + kq]     = wh0;  *(bf16x8*)&WhS[r * LDB + kq + 8] = wh1;
        *(bf16x8*)&WlS[r * LDB + kq]     = wl0;  *(bf16x8*)&WlS[r * LDB + kq + 8] = wl1;
        __syncthreads();
        #pragma unroll
        for (int ks = 0; ks < 2; ks++) {
            const int kb = ks * 32 + q * 8;
            bf16x8 fah[2], fal[2], fwh[2], fwl[2];
            #pragma unroll
            for (int mi = 0; mi < 2; mi++) {
                int row = wm + mi * 16 + l15;
                fah[mi] = *(const bf16x8*)&AhS[row * LDB + kb];
                fal[mi] = *(const bf16x8*)&AlS[row * LDB + kb];
            }
            #pragma unroll
            for (int ni = 0; ni < 2; ni++) {
                int row = wn + ni * 16 + l15;
                fwh[ni] = *(const bf16x8*)&WhS[row * LDB + kb];
                fwl[ni] = *(const bf16x8*)&WlS[row * LDB + kb];
            }
            #pragma unroll
            for (int mi = 0; mi < 2; mi++)
                #pragma unroll
                for (int ni = 0; ni < 2; ni++) {
                    acc[mi][ni] = __builtin_amdgcn_mfma_f32_16x16x32_bf16(fah[mi], fwh[ni], acc[mi][ni], 0, 0, 0);
                    acc[mi][ni] = __builtin_amdgcn_mfma_f32_16x16x32_bf16(fah[mi], fwl[ni], acc[mi][ni], 0, 0, 0);
                    acc[mi][ni] = __builtin_amdgcn_mfma_f32_16x16x32_bf16(fal[mi], fwh[ni], acc[mi][ni], 0, 0, 0);
                }
        }
    }
    #pragma unroll
    for (int ni = 0; ni < 2; ni++) {
        int col = n0 + wn + ni * 16 + l15;
        float bb = bias[col];
        #pragma unroll
        for (int mi = 0; mi < 2; mi++)
            #pragma unroll
            for (int reg = 0; reg < 4; reg++) {
                int row = m0 + wm + mi * 16 + q * 4 + reg;
                float v = fmaxf(acc[mi][ni][reg] + bb, 0.f);
                bh h, l; split2(v, h, l);
                size_t off = (size_t)row * H_ + col;
                Ch[off] = h; Cl[off] = l;
            }
    }
}

// ---------------- GEMM2: xhat = c1 @ fc2_w^T + fc2_b; 96x32 tiles; grid 8x32 = 256 blocks = 1/CU ----------------
// 384 threads = 6 waves, each wave 16 rows x 32 cols. Bit-identical K order vs 64x32 version.
__global__ __launch_bounds__(384) void gemm2_kernel(
        const bh* __restrict__ Ah_, const bh* __restrict__ Al_,  // (rows,1024) c1 hi/lo
        const float* __restrict__ W,     // (256,1024) fp32 fc2_w, split inline
        const float* __restrict__ bias,
        float* __restrict__ C, _Float16* __restrict__ C16)       // (rows,256)
{
    __shared__ __align__(16) bh AhS[96 * LDB], AlS[96 * LDB], WhS[32 * LDB], WlS[32 * LDB];  // 36.9 KB
    const int tid = threadIdx.x;
    const int m0 = blockIdx.y * 96, n0 = blockIdx.x * 32;
    const int lane = tid & 63, wv_ = tid >> 6;     // 0..5
    const int wm = wv_ * 16;
    const int l15 = lane & 15, q = lane >> 4;
    const int r = tid >> 2, kq = (tid & 3) * 16;   // A staging: 96 rows x 4 thr x 16 elems
    const int rw = (tid & 255) >> 3, kw = (tid & 7) * 8;  // W staging (tid<256): 32 rows x 8 thr x 8 floats

    f32x4 acc[2] = {};
    for (int k0 = 0; k0 < H_; k0 += 64) {
        const bh* pah = Ah_ + (size_t)(m0 + r) * H_ + k0 + kq;
        const bh* pal = Al_ + (size_t)(m0 + r) * H_ + k0 + kq;
        bf16x8 a0 = *(const bf16x8*)pah, a1 = *(const bf16x8*)(pah + 8);
        bf16x8 l0 = *(const bf16x8*)pal, l1 = *(const bf16x8*)(pal + 8);
        bf16x8 wh8, wl8;
        if (tid < 256) {
            const float* wp = W + (size_t)(n0 + rw) * H_ + k0 + kw;
            float wf[8];
            *(float4*)&wf[0] = *(const float4*)wp;
            *(float4*)&wf[4] = *(const float4*)(wp + 4);
            split8(wf, wh8, wl8);
        }
        __syncthreads();
        *(bf16x8*)&AhS[r * LDB + kq] = a0;  *(bf16x8*)&AhS[r * LDB + kq + 8] = a1;
        *(bf16x8*)&AlS[r * LDB + kq] = l0;  *(bf16x8*)&AlS[r * LDB + kq + 8] = l1;
        if (tid < 256) {
            *(bf16x8*)&WhS[rw * LDB + kw] = wh8;
            *(bf16x8*)&WlS[rw * LDB + kw] = wl8;
        }
        __syncthreads();
        #pragma unroll
        for (int ks = 0; ks < 2; ks++) {
            const int kb = ks * 32 + q * 8;
            bf16x8 fah = *(const bf16x8*)&AhS[(wm + l15) * LDB + kb];
            bf16x8 fal = *(const bf16x8*)&AlS[(wm + l15) * LDB + kb];
            #pragma unroll
            for (int ni = 0; ni < 2; ni++) {
                int row = ni * 16 + l15;
                bf16x8 fwh = *(const bf16x8*)&WhS[row * LDB + kb];
                bf16x8 fwl = *(const bf16x8*)&WlS[row * LDB + kb];
                acc[ni] = __builtin_amdgcn_mfma_f32_16x16x32_bf16(fah, fwh, acc[ni], 0, 0, 0);
                acc[ni] = __builtin_amdgcn_mfma_f32_16x16x32_bf16(fah, fwl, acc[ni], 0, 0, 0);
                acc[ni] = __builtin_amdgcn_mfma_f32_16x16x32_bf16(fal, fwh, acc[ni], 0, 0, 0);
            }
        }
    }
    #pragma unroll
    for (int ni = 0; ni < 2; ni++) {
        int col = n0 + ni * 16 + l15;
        float bb = bias[col];
        #pragma unroll
        for (int reg = 0; reg < 4; reg++) {
            int row = m0 + wm + q * 4 + reg;
            float v = acc[ni][reg] + bb;
            C[(size_t)row * D_ + col] = v;
            C16[(size_t)row * D_ + col] = (_Float16)v;
        }
    }
}

// ---------------- pairwise weighted L1 + mask + leaky (R1/R4 version, no fences) ----------------
// Upper-triangle 64x64 tiles (21/batch, 168 blocks), mirror-written.
// 512 threads. Whole D=256 staged ONCE as fp16 into k2-major LDS -> single barrier,
// then 128 barrier-free packed-fp16 iterations at 2 waves/SIMD.
#define DLX 132   // row-slot stride (128 rows + 4 pad); 528 B per k2 -> 16B-aligned, reads <=2-way banks
__global__ __launch_bounds__(512) void dist_kernel(const _Float16* __restrict__ xh16,
                                                   const float* __restrict__ w,
                                                   const int* __restrict__ box_num,
                                                   float* __restrict__ dist) {
    __shared__ __align__(16) unsigned X[128 * DLX];   // [k2][row: 0-63 = i-block, 64-127 = j-block]
    __shared__ unsigned WkS[128];
    const int bidx = blockIdx.x;
    const int b = bidx / 21;
    int p = bidx % 21;
    int ti = 0;
    while (p >= 6 - ti) { p -= 6 - ti; ti++; }
    const int tj = ti + p;
    const int i0 = ti * 64, j0 = tj * 64;
    const int tid = threadIdx.x;
    const int lane = tid & 63;

    // sum(learn_w) per wave
    float sumw = w[lane] + w[lane + 64] + w[lane + 128] + w[lane + 192];
    #pragma unroll
    for (int off = 32; off > 0; off >>= 1) sumw += __shfl_xor(sumw, off);

    // w pairs as fp16x2 in LDS
    if (tid < 128) {
        float2 wp = *(const float2*)&w[2 * tid];
        h2 wv = {(_Float16)wp.x, (_Float16)wp.y};
        WkS[tid] = __builtin_bit_cast(unsigned, wv);
    }

    // stage 128 rows x 256 dims fp16 (64 KB) transposed to k2-major
    const int sr = tid >> 2, koff = (tid & 3) * 64;
    const int grow = (sr < 64) ? (i0 + sr) : (j0 + sr - 64);
    const _Float16* src = xh16 + ((size_t)b * N_ + grow) * D_ + koff;
    #pragma unroll
    for (int ld = 0; ld < 8; ld++) {
        uint4 v = *(const uint4*)(src + ld * 8);
        int k2 = (koff >> 1) + ld * 4;
        X[(k2 + 0) * DLX + sr] = v.x;
        X[(k2 + 1) * DLX + sr] = v.y;
        X[(k2 + 2) * DLX + sr] = v.z;
        X[(k2 + 3) * DLX + sr] = v.w;
    }
    __syncthreads();   // the ONLY barrier

    const int tx = tid & 31, ty = tid >> 5;   // 16x32 thread grid, 4x2 micro
    float acc[4][2] = {};
    #pragma unroll 4
    for (int k2 = 0; k2 < 128; k2++) {
        uint4 av = *(const uint4*)&X[k2 * DLX + ty * 4];        // 4 i-rows (broadcast x32)
        uint2 bv = *(const uint2*)&X[k2 * DLX + 64 + tx * 2];   // 2 j-rows (2-way banks)
        h2 wv = __builtin_bit_cast(h2, WkS[k2]);
        h2 ai[4] = {__builtin_bit_cast(h2, av.x), __builtin_bit_cast(h2, av.y),
                    __builtin_bit_cast(h2, av.z), __builtin_bit_cast(h2, av.w)};
        h2 bj[2] = {__builtin_bit_cast(h2, bv.x), __builtin_bit_cast(h2, bv.y)};
        #pragma unroll
        for (int ii = 0; ii < 4; ii++)
            #pragma unroll
            for (int jj = 0; jj < 2; jj++) {
                h2 d = habs2(ai[ii] - bj[jj]);
                acc[ii][jj] = FDOT2(d, wv, acc[ii][jj]);
            }
    }

    const int bn = load_boxnum(box_num, b);
    float m[4][2];
    #pragma unroll
    for (int ii = 0; ii < 4; ii++) {
        int i = i0 + ty * 4 + ii;
        bool vi = i < bn;
        #pragma unroll
        for (int jj = 0; jj < 2; jj++) {
            int j = j0 + tx * 2 + jj;
            float v = acc[ii][jj];
            if (!(vi && (j < bn))) v -= sumw;
            m[ii][jj] = v > 0.f ? v : 0.01f * v;
        }
    }
    // primary tile: rows i, cols j (coalesced float2)
    #pragma unroll
    for (int ii = 0; ii < 4; ii++) {
        int i = i0 + ty * 4 + ii;
        float2 o = {m[ii][0], m[ii][1]};
        *(float2*)&dist[((size_t)b * N_ + i) * N_ + j0 + tx * 2] = o;
    }
    // mirror tile: rows j, cols i (diagonal tiles double-write identical bits - benign)
    #pragma unroll
    for (int jj = 0; jj < 2; jj++) {
        int j = j0 + tx * 2 + jj;
        float4 o = {m[0][jj], m[1][jj], m[2][jj], m[3][jj]};
        *(float4*)&dist[((size_t)b * N_ + j) * N_ + i0 + ty * 4] = o;
    }
}

// ---------------- row softmax: 4 waves per block, one row per wave ----------------
__global__ __launch_bounds__(256) void softmax_kernel(float* __restrict__ sa,
                                                      const float* __restrict__ adj) {
    const int row = blockIdx.x * 4 + (threadIdx.x >> 6);
    const int t = threadIdx.x & 63;
    float* prow = sa + (size_t)row * N_;
    const float* arow = adj + (size_t)row * N_;
    float v[6];
    float m = -1e30f;
    #pragma unroll
    for (int qq = 0; qq < 6; qq++) { v[qq] = prow[t + qq * 64]; m = fmaxf(m, v[qq]); }
    #pragma unroll
    for (int off = 32; off > 0; off >>= 1) m = fmaxf(m, __shfl_xor(m, off));
    float e[6];
    float s = 0.f;
    #pragma unroll
    for (int qq = 0; qq < 6; qq++) { e[qq] = arow[t + qq * 64] * expf(v[qq] - m); s += e[qq]; }
    #pragma unroll
    for (int off = 32; off > 0; off >>= 1) s += __shfl_xor(s, off);
    float inv = 1.0f / s;
    #pragma unroll
    for (int qq = 0; qq < 6; qq++) prow[t + qq * 64] = e[qq] * inv + 1e-10f;
}

extern "C" void kernel_launch(void* const* d_in, const int* in_sizes, int n_in,
                              void* d_out, int out_size, void* d_ws, size_t ws_size,
                              hipStream_t stream) {
    const float* x       = (const float*)d_in[0];
    const float* adj     = (const float*)d_in[1];
    const int*   box_num = (const int*)d_in[2];
    const float* fc1_w   = (const float*)d_in[3];
    const float* fc1_b   = (const float*)d_in[4];
    const float* fc2_w   = (const float*)d_in[5];
    const float* fc2_b   = (const float*)d_in[6];
    const float* learn_w = (const float*)d_in[7];

    float* soft_adj = (float*)d_out;
    float* xhat     = (float*)d_out + (size_t)B_ * N_ * N_;

    const int BN = B_ * N_;  // 3072

    // ws layout: [x16 fp16 (1.5 MB)] [chunk: c1h|c1l (bf16)]
    _Float16* xh16 = (_Float16*)d_ws;
    bh* cbase = (bh*)(xh16 + (size_t)BN * D_);
    const size_t fixed_bytes = (size_t)BN * D_ * 2;
    const size_t per_row = (size_t)H_ * 2 * 2;   // c1 hi+lo bytes per row = 4096

    long long avail = (long long)ws_size - (long long)fixed_bytes;
    long long mr = (avail > 0) ? (avail / (long long)per_row) : 0;
    if (mr > BN) mr = BN;
    mr -= mr % 192;          // chunk granularity: lcm(gemm1 64-row, gemm2 96-row)
    if (mr < 192) mr = 192;  // ws is 256 MiB in this harness; single-chunk path in practice
    const int max_rows = (int)mr;

    for (int m0 = 0; m0 < BN; m0 += max_rows) {
        int rows = BN - m0; if (rows > max_rows) rows = max_rows;
        bh* c1h = cbase;
        bh* c1l = c1h + (size_t)max_rows * H_;

        dim3 g1(H_ / 64, rows / 64);
        gemm1_kernel<<<g1, 256, 0, stream>>>(x + (size_t)m0 * D_, fc1_w, fc1_b, c1h, c1l);
        dim3 g2(D_ / 32, rows / 96);
        gemm2_kernel<<<g2, 384, 0, stream>>>(c1h, c1l, fc2_w, fc2_b,
                                             xhat + (size_t)m0 * D_, xh16 + (size_t)m0 * D_);
    }

    dist_kernel<<<B_ * 21, 512, 0, stream>>>(xh16, learn_w, box_num, soft_adj);

    softmax_kernel<<<BN / 4, 256, 0, stream>>>(soft_adj, adj);
}

// Round 8
// 124.905 us; speedup vs baseline: 1.7068x; 1.0067x over previous
//
#include <hip/hip_runtime.h>
#include <math.h>

// Problem constants (fixed by reference)
#define B_ 8
#define N_ 384
#define D_ 256
#define H_ 1024

typedef __bf16 bh;
typedef __bf16 bf16x8 __attribute__((ext_vector_type(8)));
typedef float  f32x4  __attribute__((ext_vector_type(4)));
typedef _Float16 h2 __attribute__((ext_vector_type(2)));

#define LDB  72    // LDS row stride (bf16) for 64-wide K tiles: 144 B rows, <=2-way banks
#define LDK2 136   // LDS row stride (bf16) for 128-wide K tiles: 272 B rows, same bank pattern

#if __has_builtin(__builtin_amdgcn_fdot2)
#define FDOT2(a,b,c) __builtin_amdgcn_fdot2((a),(b),(c),false)
#else
#define FDOT2(a,b,c) ((c) + (float)(a).x*(float)(b).x + (float)(a).y*(float)(b).y)
#endif

__device__ inline h2 habs2(h2 x) {
    unsigned u = __builtin_bit_cast(unsigned, x) & 0x7fff7fffu;
    return __builtin_bit_cast(h2, u);
}

// split fp32 -> hi + lo bf16 (3xbf16 trick: a*b ~= ah*bh + ah*bl + al*bh, rel err ~2^-16)
__device__ inline void split2(float v, bh& h, bh& l) {
    h = (bh)v;
    l = (bh)(v - (float)h);
}

__device__ inline void split8(const float* f, bf16x8& h8, bf16x8& l8) {
    #pragma unroll
    for (int i = 0; i < 8; i++) { bh h, l; split2(f[i], h, l); h8[i] = h; l8[i] = l; }
}

// box_num is logically int64; harness may hand int32. box_num >= 1 always, so
// int64-LE layout has all odd words zero -> runtime-detectable.
__device__ inline int load_boxnum(const int* __restrict__ p, int b) {
    bool is64 = ((p[1] | p[3] | p[5] | p[7]) == 0);
    return is64 ? p[2 * b] : p[b];
}

// ---------------- GEMM1: c1 = relu(x @ fc1_w^T + fc1_b), 64x64 tiles, inline fp32->hi/lo split ----------------
__global__ __launch_bounds__(256) void gemm1_kernel(
        const float* __restrict__ A,     // (rows,256) fp32 x
        const float* __restrict__ W,     // (1024,256) fp32 fc1_w
        const float* __restrict__ bias,
        bh* __restrict__ Ch, bh* __restrict__ Cl)   // (rows,1024) hi/lo
{
    __shared__ __align__(16) bh AhS[64 * LDB], AlS[64 * LDB], WhS[64 * LDB], WlS[64 * LDB];  // 36.9 KB
    const int tid = threadIdx.x;
    const int m0 = blockIdx.y * 64, n0 = blockIdx.x * 64;
    const int r = tid >> 2, kq = (tid & 3) * 16;   // staging: 4 threads/row x 16 elems
    const int lane = tid & 63, wv_ = tid >> 6;
    const int wm = (wv_ & 1) * 32, wn = (wv_ >> 1) * 32;
    const int l15 = lane & 15, q = lane >> 4;

    f32x4 acc[2][2] = {};
    for (int k0 = 0; k0 < D_; k0 += 64) {
        const float* ap = A + (size_t)(m0 + r) * D_ + k0 + kq;
        const float* wp = W + (size_t)(n0 + r) * D_ + k0 + kq;
        float af[16], wf[16];
        #pragma unroll
        for (int u = 0; u < 4; u++) {
            *(float4*)&af[4 * u] = *(const float4*)(ap + 4 * u);
            *(float4*)&wf[4 * u] = *(const float4*)(wp + 4 * u);
        }
        bf16x8 ah0, ah1, al0, al1, wh0, wh1, wl0, wl1;
        split8(af,     ah0, al0); split8(af + 8, ah1, al1);
        split8(wf,     wh0, wl0); split8(wf + 8, wh1, wl1);
        __syncthreads();
        *(bf16x8*)&AhS[r * LDB + kq]     = ah0;  *(bf16x8*)&AhS[r * LDB + kq + 8] = ah1;
        *(bf16x8*)&AlS[r * LDB + kq]     = al0;  *(bf16x8*)&AlS[r * LDB + kq + 8] = al1;
        *(bf16x8*)&WhS[r * LDB + kq]     = wh0;  *(bf16x8*)&WhS[r * LDB + kq + 8] = wh1;
        *(bf16x8*)&WlS[r * LDB + kq]     = wl0;  *(bf16x8*)&WlS[r * LDB + kq + 8] = wl1;
        __syncthreads();
        #pragma unroll
        for (int ks = 0; ks < 2; ks++) {
            const int kb = ks * 32 + q * 8;
            bf16x8 fah[2], fal[2], fwh[2], fwl[2];
            #pragma unroll
            for (int mi = 0; mi < 2; mi++) {
                int row = wm + mi * 16 + l15;
                fah[mi] = *(const bf16x8*)&AhS[row * LDB + kb];
                fal[mi] = *(const bf16x8*)&AlS[row * LDB + kb];
            }
            #pragma unroll
            for (int ni = 0; ni < 2; ni++) {
                int row = wn + ni * 16 + l15;
                fwh[ni] = *(const bf16x8*)&WhS[row * LDB + kb];
                fwl[ni] = *(const bf16x8*)&WlS[row * LDB + kb];
            }
            #pragma unroll
            for (int mi = 0; mi < 2; mi++)
                #pragma unroll
                for (int ni = 0; ni < 2; ni++) {
                    acc[mi][ni] = __builtin_amdgcn_mfma_f32_16x16x32_bf16(fah[mi], fwh[ni], acc[mi][ni], 0, 0, 0);
                    acc[mi][ni] = __builtin_amdgcn_mfma_f32_16x16x32_bf16(fah[mi], fwl[ni], acc[mi][ni], 0, 0, 0);
                    acc[mi][ni] = __builtin_amdgcn_mfma_f32_16x16x32_bf16(fal[mi], fwh[ni], acc[mi][ni], 0, 0, 0);
                }
        }
    }
    #pragma unroll
    for (int ni = 0; ni < 2; ni++) {
        int col = n0 + wn + ni * 16 + l15;
        float bb = bias[col];
        #pragma unroll
        for (int mi = 0; mi < 2; mi++)
            #pragma unroll
            for (int reg = 0; reg < 4; reg++) {
                int row = m0 + wm + mi * 16 + q * 4 + reg;
                float v = fmaxf(acc[mi][ni][reg] + bb, 0.f);
                bh h, l; split2(v, h, l);
                size_t off = (size_t)row * H_ + col;
                Ch[off] = h; Cl[off] = l;
            }
    }
}

// ---------------- GEMM2: xhat = c1 @ fc2_w^T + fc2_b; 64x32 tiles; K-stage 128 (16 barriers) ----------------
__global__ __launch_bounds__(256) void gemm2_kernel(
        const bh* __restrict__ Ah_, const bh* __restrict__ Al_,  // (rows,1024) c1 hi/lo
        const float* __restrict__ W,     // (256,1024) fp32 fc2_w, split inline
        const float* __restrict__ bias,
        float* __restrict__ C, _Float16* __restrict__ C16)       // (rows,256)
{
    __shared__ __align__(16) bh AhS[64 * LDK2], AlS[64 * LDK2], WhS[32 * LDK2], WlS[32 * LDK2];  // 52.2 KB
    const int tid = threadIdx.x;
    const int m0 = blockIdx.y * 64, n0 = blockIdx.x * 32;
    const int lane = tid & 63, wv_ = tid >> 6;
    const int wm = wv_ * 16;                       // 4 waves x 16 rows, full 32 cols each
    const int l15 = lane & 15, q = lane >> 4;
    const int r = tid >> 2, kq = (tid & 3) * 32;   // A staging: 4 thr/row x 32 elems
    const int rw = tid >> 3, kw = (tid & 7) * 16;  // W staging: 8 thr/row x 16 elems

    f32x4 acc[2] = {};
    for (int k0 = 0; k0 < H_; k0 += 128) {
        const bh* pah = Ah_ + (size_t)(m0 + r) * H_ + k0 + kq;
        const bh* pal = Al_ + (size_t)(m0 + r) * H_ + k0 + kq;
        bf16x8 va[4], vl[4];
        #pragma unroll
        for (int u = 0; u < 4; u++) {
            va[u] = *(const bf16x8*)(pah + 8 * u);
            vl[u] = *(const bf16x8*)(pal + 8 * u);
        }
        const float* wp = W + (size_t)(n0 + rw) * H_ + k0 + kw;
        float wf[16];
        #pragma unroll
        for (int u = 0; u < 4; u++) *(float4*)&wf[4 * u] = *(const float4*)(wp + 4 * u);
        bf16x8 wh0, wh1, wl0, wl1;
        split8(wf,     wh0, wl0); split8(wf + 8, wh1, wl1);
        __syncthreads();
        #pragma unroll
        for (int u = 0; u < 4; u++) {
            *(bf16x8*)&AhS[r * LDK2 + kq + 8 * u] = va[u];
            *(bf16x8*)&AlS[r * LDK2 + kq + 8 * u] = vl[u];
        }
        *(bf16x8*)&WhS[rw * LDK2 + kw]     = wh0;  *(bf16x8*)&WhS[rw * LDK2 + kw + 8] = wh1;
        *(bf16x8*)&WlS[rw * LDK2 + kw]     = wl0;  *(bf16x8*)&WlS[rw * LDK2 + kw + 8] = wl1;
        __syncthreads();
        #pragma unroll
        for (int ks = 0; ks < 4; ks++) {
            const int kb = ks * 32 + q * 8;
            const int arow = wm + l15;
            bf16x8 fah = *(const bf16x8*)&AhS[arow * LDK2 + kb];
            bf16x8 fal = *(const bf16x8*)&AlS[arow * LDK2 + kb];
            #pragma unroll
            for (int ni = 0; ni < 2; ni++) {
                int row = ni * 16 + l15;
                bf16x8 fwh = *(const bf16x8*)&WhS[row * LDK2 + kb];
                bf16x8 fwl = *(const bf16x8*)&WlS[row * LDK2 + kb];
                acc[ni] = __builtin_amdgcn_mfma_f32_16x16x32_bf16(fah, fwh, acc[ni], 0, 0, 0);
                acc[ni] = __builtin_amdgcn_mfma_f32_16x16x32_bf16(fah, fwl, acc[ni], 0, 0, 0);
                acc[ni] = __builtin_amdgcn_mfma_f32_16x16x32_bf16(fal, fwh, acc[ni], 0, 0, 0);
            }
        }
    }
    #pragma unroll
    for (int ni = 0; ni < 2; ni++) {
        int col = n0 + ni * 16 + l15;
        float bb = bias[col];
        #pragma unroll
        for (int reg = 0; reg < 4; reg++) {
            int row = m0 + wm + q * 4 + reg;
            float v = acc[ni][reg] + bb;
            C[(size_t)row * D_ + col] = v;
            C16[(size_t)row * D_ + col] = (_Float16)v;
        }
    }
}

// ---------------- pairwise weighted L1 + mask + leaky ----------------
// Upper-triangle 64x64 tiles (21/batch, 168 blocks), mirror-written.
// 512 threads. Whole D=256 staged ONCE as fp16 into k2-major LDS -> single barrier,
// then 128 barrier-free packed-fp16 iterations at 2 waves/SIMD.
#define DLX 132   // row-slot stride (128 rows + 4 pad); 528 B per k2 -> 16B-aligned, reads <=2-way banks
__global__ __launch_bounds__(512) void dist_kernel(const _Float16* __restrict__ xh16,
                                                   const float* __restrict__ w,
                                                   const int* __restrict__ box_num,
                                                   float* __restrict__ dist) {
    __shared__ __align__(16) unsigned X[128 * DLX];   // [k2][row: 0-63 = i-block, 64-127 = j-block]
    __shared__ unsigned WkS[128];
    const int bidx = blockIdx.x;
    const int b = bidx / 21;
    int p = bidx % 21;
    int ti = 0;
    while (p >= 6 - ti) { p -= 6 - ti; ti++; }
    const int tj = ti + p;
    const int i0 = ti * 64, j0 = tj * 64;
    const int tid = threadIdx.x;
    const int lane = tid & 63;

    // sum(learn_w) per wave
    float sumw = w[lane] + w[lane + 64] + w[lane + 128] + w[lane + 192];
    #pragma unroll
    for (int off = 32; off > 0; off >>= 1) sumw += __shfl_xor(sumw, off);

    // w pairs as fp16x2 in LDS
    if (tid < 128) {
        float2 wp = *(const float2*)&w[2 * tid];
        h2 wv = {(_Float16)wp.x, (_Float16)wp.y};
        WkS[tid] = __builtin_bit_cast(unsigned, wv);
    }

    // stage 128 rows x 256 dims fp16 (64 KB) transposed to k2-major
    const int sr = tid >> 2, koff = (tid & 3) * 64;
    const int grow = (sr < 64) ? (i0 + sr) : (j0 + sr - 64);
    const _Float16* src = xh16 + ((size_t)b * N_ + grow) * D_ + koff;
    #pragma unroll
    for (int ld = 0; ld < 8; ld++) {
        uint4 v = *(const uint4*)(src + ld * 8);
        int k2 = (koff >> 1) + ld * 4;
        X[(k2 + 0) * DLX + sr] = v.x;
        X[(k2 + 1) * DLX + sr] = v.y;
        X[(k2 + 2) * DLX + sr] = v.z;
        X[(k2 + 3) * DLX + sr] = v.w;
    }
    __syncthreads();   // the ONLY barrier

    const int tx = tid & 31, ty = tid >> 5;   // 16x32 thread grid, 4x2 micro
    float acc[4][2] = {};
    #pragma unroll 4
    for (int k2 = 0; k2 < 128; k2++) {
        uint4 av = *(const uint4*)&X[k2 * DLX + ty * 4];        // 4 i-rows (broadcast x32)
        uint2 bv = *(const uint2*)&X[k2 * DLX + 64 + tx * 2];   // 2 j-rows (2-way banks)
        h2 wv = __builtin_bit_cast(h2, WkS[k2]);
        h2 ai[4] = {__builtin_bit_cast(h2, av.x), __builtin_bit_cast(h2, av.y),
                    __builtin_bit_cast(h2, av.z), __builtin_bit_cast(h2, av.w)};
        h2 bj[2] = {__builtin_bit_cast(h2, bv.x), __builtin_bit_cast(h2, bv.y)};
        #pragma unroll
        for (int ii = 0; ii < 4; ii++)
            #pragma unroll
            for (int jj = 0; jj < 2; jj++) {
                h2 d = habs2(ai[ii] - bj[jj]);
                acc[ii][jj] = FDOT2(d, wv, acc[ii][jj]);
            }
    }

    const int bn = load_boxnum(box_num, b);
    float m[4][2];
    #pragma unroll
    for (int ii = 0; ii < 4; ii++) {
        int i = i0 + ty * 4 + ii;
        bool vi = i < bn;
        #pragma unroll
        for (int jj = 0; jj < 2; jj++) {
            int j = j0 + tx * 2 + jj;
            float v = acc[ii][jj];
            if (!(vi && (j < bn))) v -= sumw;
            m[ii][jj] = v > 0.f ? v : 0.01f * v;
        }
    }
    // primary tile: rows i, cols j (coalesced float2)
    #pragma unroll
    for (int ii = 0; ii < 4; ii++) {
        int i = i0 + ty * 4 + ii;
        float2 o = {m[ii][0], m[ii][1]};
        *(float2*)&dist[((size_t)b * N_ + i) * N_ + j0 + tx * 2] = o;
    }
    // mirror tile: rows j, cols i (diagonal tiles double-write identical bits - benign)
    #pragma unroll
    for (int jj = 0; jj < 2; jj++) {
        int j = j0 + tx * 2 + jj;
        float4 o = {m[0][jj], m[1][jj], m[2][jj], m[3][jj]};
        *(float4*)&dist[((size_t)b * N_ + j) * N_ + i0 + ty * 4] = o;
    }
}

// ---------------- row softmax: 4 waves per block, one row per wave ----------------
__global__ __launch_bounds__(256) void softmax_kernel(float* __restrict__ sa,
                                                      const float* __restrict__ adj) {
    const int row = blockIdx.x * 4 + (threadIdx.x >> 6);
    const int t = threadIdx.x & 63;
    float* prow = sa + (size_t)row * N_;
    const float* arow = adj + (size_t)row * N_;
    float v[6];
    float m = -1e30f;
    #pragma unroll
    for (int qq = 0; qq < 6; qq++) { v[qq] = prow[t + qq * 64]; m = fmaxf(m, v[qq]); }
    #pragma unroll
    for (int off = 32; off > 0; off >>= 1) m = fmaxf(m, __shfl_xor(m, off));
    float e[6];
    float s = 0.f;
    #pragma unroll
    for (int qq = 0; qq < 6; qq++) { e[qq] = arow[t + qq * 64] * expf(v[qq] - m); s += e[qq]; }
    #pragma unroll
    for (int off = 32; off > 0; off >>= 1) s += __shfl_xor(s, off);
    float inv = 1.0f / s;
    #pragma unroll
    for (int qq = 0; qq < 6; qq++) prow[t + qq * 64] = e[qq] * inv + 1e-10f;
}

extern "C" void kernel_launch(void* const* d_in, const int* in_sizes, int n_in,
                              void* d_out, int out_size, void* d_ws, size_t ws_size,
                              hipStream_t stream) {
    const float* x       = (const float*)d_in[0];
    const float* adj     = (const float*)d_in[1];
    const int*   box_num = (const int*)d_in[2];
    const float* fc1_w   = (const float*)d_in[3];
    const float* fc1_b   = (const float*)d_in[4];
    const float* fc2_w   = (const float*)d_in[5];
    const float* fc2_b   = (const float*)d_in[6];
    const float* learn_w = (const float*)d_in[7];

    float* soft_adj = (float*)d_out;
    float* xhat     = (float*)d_out + (size_t)B_ * N_ * N_;

    const int BN = B_ * N_;  // 3072

    // ws layout: [x16 fp16 (1.5 MB)] [chunk: c1h|c1l (bf16)]
    _Float16* xh16 = (_Float16*)d_ws;
    bh* cbase = (bh*)(xh16 + (size_t)BN * D_);
    const size_t fixed_bytes = (size_t)BN * D_ * 2;
    const size_t per_row = (size_t)H_ * 2 * 2;   // c1 hi+lo bytes per row = 4096

    long long avail = (long long)ws_size - (long long)fixed_bytes;
    long long mr = (avail > 0) ? (avail / (long long)per_row) : 0;
    if (mr > BN) mr = BN;
    mr &= ~63LL;
    if (mr < 64) mr = 64;    // ws is 256 MiB in this harness; single-chunk path in practice
    const int max_rows = (int)mr;

    for (int m0 = 0; m0 < BN; m0 += max_rows) {
        int rows = BN - m0; if (rows > max_rows) rows = max_rows;
        bh* c1h = cbase;
        bh* c1l = c1h + (size_t)max_rows * H_;

        dim3 g1(H_ / 64, rows / 64);
        gemm1_kernel<<<g1, 256, 0, stream>>>(x + (size_t)m0 * D_, fc1_w, fc1_b, c1h, c1l);
        dim3 g2(D_ / 32, rows / 64);
        gemm2_kernel<<<g2, 256, 0, stream>>>(c1h, c1l, fc2_w, fc2_b,
                                             xhat + (size_t)m0 * D_, xh16 + (size_t)m0 * D_);
    }

    dist_kernel<<<B_ * 21, 512, 0, stream>>>(xh16, learn_w, box_num, soft_adj);

    softmax_kernel<<<BN / 4, 256, 0, stream>>>(soft_adj, adj);
}